// Round 2
// baseline (80.465 us; speedup 1.0000x reference)
//
#include <hip/hip_runtime.h>

// dynoNet G-block, B=128 T=4096 I=8 O=8, NB=NA=3.
// |a|<=0.01 -> combined impulse response h = b (*) d decays fast; truncate at
// KT=8 taps (tail sum <= 1.3e-6, worst-case output err ~6e-5 << 3.09e-3).
// Collapses to parallel causal FIR: out[b,t,o] = sum_i sum_{k<8} H[i,o,k]*u[b,t-k,i]
//
// R4 (this round): taps are WAVE-UNIFORM -> move them off the LDS pipe.
//   - tiny producer kernel computes H[I][KT][O] (512 f32) into d_ws once per
//     iteration (stream-ordered before main kernel; graph-safe, no syncs).
//   - main kernel reads taps via uniform-address const pointer -> scalar
//     s_load / L1 broadcast on SMEM/VMEM pipe; eliminates 128 of the 152
//     ds_read_b128 per wave (R1 model: LDS pipe 16K cyc/CU -> ~4K).
//   - taps for each i staged in h[16] float4 regs (static idx, no scratch),
//     #pragma unroll 2 on i-loop for cross-iteration load hoisting.
// Geometry unchanged from R3: NTH=128, RPT=4, TILE=512, 1024 blocks.

constexpr int B_   = 128;
constexpr int T_   = 4096;
constexpr int I_   = 8;
constexpr int O_   = 8;
constexpr int KT   = 8;                  // truncated impulse-response taps
constexpr int TILE = 512;                // t-rows per block
constexpr int HALO = 8;                  // >= KT-1, even
constexpr int WROW = TILE + HALO + 4;    // 524 floats per i-plane (16B-aligned rows)
constexpr int NTH  = 128;
constexpr int RPT  = 4;                  // consecutive t-rows per thread
constexpr int NLD  = ((TILE + HALO) * 2 + NTH - 1) / NTH;  // 9 staged float4/thread

// ---- producer: effective FIR taps H[i][k][o] from (num, den) ----
__global__ __launch_bounds__(64)
void tap_build_kernel(const float* __restrict__ num, const float* __restrict__ den,
                      float* __restrict__ H) {
  const int tid = threadIdx.x;           // one thread per (i,o), tid = i*O_+o
  const float* bc = num + tid * 3;       // layout [I][O][3]
  const float* ac = den + tid * 3;
  const float b0 = bc[0], b1 = bc[1], b2 = bc[2];
  const float a0 = ac[0], a1 = ac[1], a2 = ac[2];
  float d[KT];
  d[0] = 1.0f;
  d[1] = -a0;
  d[2] = -(a0 * d[1] + a1);
  #pragma unroll
  for (int k = 3; k < KT; ++k)
    d[k] = -(a0 * d[k - 1] + a1 * d[k - 2] + a2 * d[k - 3]);
  const int i = tid >> 3, o = tid & 7;
  #pragma unroll
  for (int k = 0; k < KT; ++k) {
    float h = b0 * d[k];
    if (k >= 1) h = fmaf(b1, d[k - 1], h);
    if (k >= 2) h = fmaf(b2, d[k - 2], h);
    H[i * (KT * O_) + k * O_ + o] = h;
  }
}

__global__ __launch_bounds__(NTH)
void dyno_fir_kernel(const float* __restrict__ u, const float* __restrict__ Hg,
                     float* __restrict__ out) {
  __shared__ float Us[I_ * WROW];        // u tile, transposed [i][t_local]

  const int tid = threadIdx.x;
  const int b   = blockIdx.x >> 3;       // T_/TILE == 8 tiles per sequence
  const int t0  = (blockIdx.x & 7) * TILE;

  // ---- stage u tile: issue ALL global loads, then do LDS writes ----
  const float* ub = u + (size_t)b * (T_ * I_);
  float4 v[NLD];
  #pragma unroll
  for (int j = 0; j < NLD; ++j) {
    const int idx = tid + j * NTH;
    float4 vv = make_float4(0.f, 0.f, 0.f, 0.f);
    if (idx < (TILE + HALO) * 2) {
      const int lt = idx >> 1;           // local t in [0, TILE+HALO)
      const int i0 = (idx & 1) * 4;
      const int t  = t0 - HALO + lt;
      if (t >= 0) vv = *reinterpret_cast<const float4*>(ub + (size_t)t * I_ + i0);
    }
    v[j] = vv;
  }
  #pragma unroll
  for (int j = 0; j < NLD; ++j) {
    const int idx = tid + j * NTH;
    if (idx < (TILE + HALO) * 2) {
      const int lt = idx >> 1;
      const int i0 = (idx & 1) * 4;
      Us[(i0 + 0) * WROW + lt] = v[j].x;
      Us[(i0 + 1) * WROW + lt] = v[j].y;
      Us[(i0 + 2) * WROW + lt] = v[j].z;
      Us[(i0 + 3) * WROW + lt] = v[j].w;
    }
  }
  __syncthreads();

  // ---- FIR compute: 4 consecutive t, all 8 o, accumulate over i,k ----
  float acc[RPT][O_];
  #pragma unroll
  for (int r = 0; r < RPT; ++r)
    #pragma unroll
    for (int o = 0; o < O_; ++o) acc[r][o] = 0.f;

  const int base = tid * RPT;            // output rows t0+base .. t0+base+3
  const float4* __restrict__ Hg4 = reinterpret_cast<const float4*>(Hg);

  #pragma unroll 2
  for (int i = 0; i < I_; ++i) {
    // taps for this i: 16 float4, wave-uniform address -> scalar/L1 broadcast,
    // NOT the LDS pipe. Static indices -> registers (no scratch).
    float4 h[2 * KT];
    const float4* Hp = Hg4 + i * (2 * KT);
    #pragma unroll
    for (int j = 0; j < 2 * KT; ++j) h[j] = Hp[j];

    // window: Us[i][base + j], j = 0..11; value for row (base+r) lag k is w[8+r-k]
    float w[12];
    const float4* Wp = reinterpret_cast<const float4*>(&Us[i * WROW + base]);
    #pragma unroll
    for (int j = 0; j < 3; ++j)
      *reinterpret_cast<float4*>(&w[4 * j]) = Wp[j];   // 16B-aligned ds_read_b128

    #pragma unroll
    for (int k = 0; k < KT; ++k) {
      const float4 cA = h[2 * k];        // taps o=0..3
      const float4 cB = h[2 * k + 1];    // taps o=4..7
      #pragma unroll
      for (int r = 0; r < RPT; ++r) {
        const float uv = w[8 + r - k];
        acc[r][0] = fmaf(cA.x, uv, acc[r][0]);
        acc[r][1] = fmaf(cA.y, uv, acc[r][1]);
        acc[r][2] = fmaf(cA.z, uv, acc[r][2]);
        acc[r][3] = fmaf(cA.w, uv, acc[r][3]);
        acc[r][4] = fmaf(cB.x, uv, acc[r][4]);
        acc[r][5] = fmaf(cB.y, uv, acc[r][5]);
        acc[r][6] = fmaf(cB.z, uv, acc[r][6]);
        acc[r][7] = fmaf(cB.w, uv, acc[r][7]);
      }
    }
  }

  // ---- store: 4 contiguous rows of 8 floats per thread (128B/thread) ----
  float* ob = out + ((size_t)b * T_ + t0 + base) * O_;
  #pragma unroll
  for (int r = 0; r < RPT; ++r) {
    *reinterpret_cast<float4*>(ob + r * O_) =
        make_float4(acc[r][0], acc[r][1], acc[r][2], acc[r][3]);
    *reinterpret_cast<float4*>(ob + r * O_ + 4) =
        make_float4(acc[r][4], acc[r][5], acc[r][6], acc[r][7]);
  }
}

extern "C" void kernel_launch(void* const* d_in, const int* in_sizes, int n_in,
                              void* d_out, int out_size, void* d_ws, size_t ws_size,
                              hipStream_t stream) {
  const float* u   = (const float*)d_in[0];   // [B, T, I] fp32
  const float* num = (const float*)d_in[1];   // [I, O, 3] fp32
  const float* den = (const float*)d_in[2];   // [I, O, 3] fp32
  float* out = (float*)d_out;                 // [B, T, O] fp32
  float* H   = (float*)d_ws;                  // [I, KT, O] effective taps (2 KB)

  // producer (1 block, 64 threads) -> main kernel; same stream => ordered,
  // cross-XCD visibility guaranteed at dispatch boundary. No host syncs.
  tap_build_kernel<<<dim3(1), dim3(64), 0, stream>>>(num, den, H);

  dim3 grid(B_ * (T_ / TILE));                // 1024 blocks, 4 per CU
  dyno_fir_kernel<<<grid, NTH, 0, stream>>>(u, H, out);
}